// Round 8
// baseline (339.946 us; speedup 1.0000x reference)
//
#include <hip/hip_runtime.h>
#include <hip/hip_cooperative_groups.h>
#include <math.h>

namespace cg = cooperative_groups;

#define NN      512
#define EE      16384
#define NDIM    64
#define HID     128
#define FFD     2048
#define VOCAB   50
#define SEQ     100

// quantum embedding constants: (cos(.05)-sin(.05)), cos(.1), sin(.1)
#define QA 0.94877109112428797f
#define QB 0.99500416527802582f
#define QC 0.099833416646828155f

struct GArgs {
    // inputs
    const int* ei;
    const float* x; const float* g1w; const float* g1b;
    const float* g2w; const float* g2b;
    const float* fcw; const float* fcb;
    const float* saw; const float* sab;
    const float* caw; const float* cab;
    const float* lnw; const float* lnb;
    const float* fw1; const float* fb1; const float* fw2; const float* fb2;
    const float* ow; const float* ob;
    float* out;
    // workspace
    int* cnt; int* offs; int* cursor; int* csr;
    float* dinv; float* pre1; float* pre2; float* t0; float* t2; float* ca1;
    float* Msa1; float* Mca0; float* Mca1; float* Mfc0; float* Mfc1; float* sa0bias;
    float* part;
};

// ---------------- helpers ----------------

__device__ __forceinline__ float gather_row(const float* __restrict__ pre,
                                            const float* __restrict__ dinv,
                                            const int* __restrict__ offs,
                                            const int* __restrict__ csr,
                                            int row, int j) {
    float dd = dinv[row];
    float acc = pre[row * HID + j] * dd;
    int i = offs[row], e = offs[row + 1];
    for (; i + 3 < e; i += 4) {
        int s0 = csr[i], s1 = csr[i + 1], s2 = csr[i + 2], s3 = csr[i + 3];
        float a0 = pre[s0 * HID + j] * dinv[s0];
        float a1 = pre[s1 * HID + j] * dinv[s1];
        float a2 = pre[s2 * HID + j] * dinv[s2];
        float a3 = pre[s3 * HID + j] * dinv[s3];
        acc += (a0 + a1) + (a2 + a3);
    }
    for (; i < e; ++i) {
        int s = csr[i];
        acc += pre[s * HID + j] * dinv[s];
    }
    return acc * dd;
}

// layernorm for 4-rows-per-512-thread-block layout; sh = 16 floats scratch
__device__ __forceinline__ float rowln4(float v, float w, float b, float* sh, int t) {
    int r = t >> 7;                  // 0..3
    float s1 = v, s2 = v * v;
#pragma unroll
    for (int o = 32; o > 0; o >>= 1) {
        s1 += __shfl_down(s1, o);
        s2 += __shfl_down(s2, o);
    }
    int wv = (t >> 6) & 1;           // wave within row
    if ((t & 63) == 0) { sh[r * 4 + wv] = s1; sh[r * 4 + 2 + wv] = s2; }
    __syncthreads();
    float mean = (sh[r * 4] + sh[r * 4 + 1]) * (1.0f / HID);
    float m2   = (sh[r * 4 + 2] + sh[r * 4 + 3]) * (1.0f / HID);
    float rstd = rsqrtf(m2 - mean * mean + 1e-5f);
    float out = (v - mean) * rstd * w + b;
    __syncthreads();
    return out;
}

// fused FF (128->2048->128) slice, split-K partials (R5's proven 16-row shape)
__device__ __forceinline__ void ff_block(const float* __restrict__ tin,
                                         const float* __restrict__ W1,
                                         const float* __restrict__ b1,
                                         const float* __restrict__ W2,
                                         float* __restrict__ part,
                                         float* smem, int bid, int t) {
    float* sh_t = smem;          // 16*128 = 2048 floats
    float* sh_m = smem + 2048;   // 16*256 = 4096 floats
    int kc = bid & 7, rg = bid >> 3;          // rg 0..31
    int row0 = rg * 16, c0 = kc * 256;

    {   // load 16x128 input rows = 512 float4, one per thread
        float4 v = ((const float4*)(tin + row0 * HID))[t];
        ((float4*)sh_t)[t] = v;
    }
    __syncthreads();

    // phase 1: mid[16][256] = relu(t @ W1 + b1); thread = 2 rows x 4 cols
    {
        int rg2  = t >> 6;            // 0..7 -> rows 2*rg2, 2*rg2+1
        int col4 = (t & 63) * 4;
        float4 bias = *(const float4*)&b1[c0 + col4];
        float a00 = bias.x, a01 = bias.y, a02 = bias.z, a03 = bias.w;
        float a10 = bias.x, a11 = bias.y, a12 = bias.z, a13 = bias.w;
        const float* w1p = W1 + c0 + col4;
        const float* x0 = sh_t + (2 * rg2) * HID;
        const float* x1 = x0 + HID;
#pragma unroll 8
        for (int k = 0; k < HID; k++) {
            float4 w = *(const float4*)&w1p[k * FFD];
            float s0 = x0[k], s1 = x1[k];
            a00 = fmaf(s0, w.x, a00); a01 = fmaf(s0, w.y, a01);
            a02 = fmaf(s0, w.z, a02); a03 = fmaf(s0, w.w, a03);
            a10 = fmaf(s1, w.x, a10); a11 = fmaf(s1, w.y, a11);
            a12 = fmaf(s1, w.z, a12); a13 = fmaf(s1, w.w, a13);
        }
        float4 m0, m1;
        m0.x = fmaxf(a00, 0.f); m0.y = fmaxf(a01, 0.f);
        m0.z = fmaxf(a02, 0.f); m0.w = fmaxf(a03, 0.f);
        m1.x = fmaxf(a10, 0.f); m1.y = fmaxf(a11, 0.f);
        m1.z = fmaxf(a12, 0.f); m1.w = fmaxf(a13, 0.f);
        *(float4*)&sh_m[(2 * rg2) * 256 + col4]     = m0;
        *(float4*)&sh_m[(2 * rg2 + 1) * 256 + col4] = m1;
    }
    __syncthreads();

    // phase 2: partial out[16][128] = mid @ W2 slice; thread = 1 row x 4 cols
    {
        int rowg = t >> 5;            // 0..15
        int col4 = (t & 31) * 4;
        float a0 = 0.f, a1 = 0.f, a2 = 0.f, a3 = 0.f;
        const float* w2p = W2 + c0 * HID + col4;
        const float* mp = sh_m + rowg * 256;
#pragma unroll 8
        for (int kk = 0; kk < 256; kk++) {
            float4 w = *(const float4*)&w2p[kk * HID];
            float m = mp[kk];
            a0 = fmaf(m, w.x, a0); a1 = fmaf(m, w.y, a1);
            a2 = fmaf(m, w.z, a2); a3 = fmaf(m, w.w, a3);
        }
        float4 o; o.x = a0; o.y = a1; o.z = a2; o.w = a3;
        *(float4*)&part[kc * (NN * HID) + (row0 + rowg) * HID + col4] = o;
    }
}

// ---------------- the mega-kernel ----------------

__global__ __launch_bounds__(512)
void k_mega(GArgs a) {
    cg::grid_group grid = cg::this_grid();
    __shared__ __align__(16) float smem[6144];   // 24 KB, re-purposed per phase
    int bid = blockIdx.x, t = threadIdx.x;

    // ======== P1: hist | qx+GCN1 mm | comb1 x3 | sa0bias ========
    if (bid < 32) {                              // hist: 32 blk x 512 edges
        int e = bid * 512 + t;
        atomicAdd(&a.cnt[a.ei[EE + e]], 1);
    } else if (bid < 96) {                       // mm1: 64 blk x 8 rows, qx inline
        int row0 = (bid - 32) * 8;
        float* qxs = smem;                       // [8][64]
        {
            float v = a.x[row0 * NDIM + t];
            qxs[t] = QA * (QB * v + QC * tanhf(v));
        }
        __syncthreads();
        int col = t & 127, r0 = t >> 7;          // rows r0, r0+4
#pragma unroll
        for (int rr = 0; rr < 2; rr++) {
            int r = r0 + rr * 4;
            float acc = 0.0f;
#pragma unroll 8
            for (int k = 0; k < NDIM; k++)
                acc = fmaf(qxs[r * 64 + k], a.g1w[k * HID + col], acc);
            a.pre1[(row0 + r) * HID + col] = acc;
        }
    } else if (bid < 195) {                      // comb1: 33 blk per matrix
        int q = bid - 96;
        int jm = q / 33;
        int i = (q - jm * 33) * 512 + t;
        if (i < 129 * HID) {
            const float* A  = (jm == 0) ? (a.saw + (4 + 2) * HID * HID)
                             : (jm == 1) ? (a.caw + 2 * HID * HID)
                                         : (a.caw + (4 + 2) * HID * HID);
            const float* ab = (jm == 0) ? (a.sab + (4 + 2) * HID)
                             : (jm == 1) ? (a.cab + 2 * HID)
                                         : (a.cab + (4 + 2) * HID);
            const float* Bm = (jm == 0) ? (a.saw + (4 + 3) * HID * HID)
                             : (jm == 1) ? (a.caw + 3 * HID * HID)
                                         : (a.caw + (4 + 3) * HID * HID);
            const float* bb = (jm == 0) ? (a.sab + (4 + 3) * HID)
                             : (jm == 1) ? (a.cab + 3 * HID)
                                         : (a.cab + (4 + 3) * HID);
            float* outM = (jm == 0) ? a.Msa1 : (jm == 1) ? a.Mca0 : a.Mca1;
            int rw = i >> 7, col = i & 127;
            float acc;
            if (rw < 128) {
                const float* ar = A + rw * HID;
                acc = 0.0f;
#pragma unroll 8
                for (int k = 0; k < HID; k++) acc = fmaf(ar[k], Bm[k * HID + col], acc);
            } else {
                acc = bb[col];
#pragma unroll 8
                for (int k = 0; k < HID; k++) acc = fmaf(ab[k], Bm[k * HID + col], acc);
            }
            outM[i] = acc;
        }
    } else if (bid == 195) {                     // sa0 bias row
        if (t < HID) {
            const float* ab3 = a.sab + 2 * HID;
            const float* B3  = a.saw + 3 * HID * HID;
            float acc = a.sab[3 * HID + t];
#pragma unroll 8
            for (int k = 0; k < HID; k++) acc = fmaf(ab3[k], B3[k * HID + t], acc);
            a.sa0bias[t] = acc;
        }
    }
    grid.sync();

    // ======== P2: scan (blk 0) | comb2 fold fc (65 blk) ========
    if (bid == 0) {
        int* sh = (int*)smem;
        int c = a.cnt[t];
        sh[t] = c;
        __syncthreads();
        int v = c;
        for (int o = 1; o < 512; o <<= 1) {
            int add = (t >= o) ? sh[t - o] : 0;
            __syncthreads();
            v += add;
            sh[t] = v;
            __syncthreads();
        }
        a.offs[t + 1] = v;
        if (t == 0) a.offs[0] = 0;
        a.cursor[t] = v - c;
        a.dinv[t] = rsqrtf((float)c + 1.0f);
    } else if (bid <= 65) {
        int i = (bid - 1) * 512 + t;
        if (i < 2 * 129 * HID) {
            int jm = (i >= 129 * HID) ? 1 : 0;
            int ii = i - jm * 129 * HID;
            const float* M = jm ? a.Mca1 : a.Mca0;
            float* o = jm ? a.Mfc1 : a.Mfc0;
            int rw = ii >> 7, col = ii & 127;
            float acc;
            if (rw < 128) {
                const float* ar = a.fcw + rw * HID;
                acc = 0.0f;
#pragma unroll 8
                for (int k = 0; k < HID; k++) acc = fmaf(ar[k], M[k * HID + col], acc);
            } else {
                acc = M[128 * HID + col];
#pragma unroll 8
                for (int k = 0; k < HID; k++) acc = fmaf(a.fcb[k], M[k * HID + col], acc);
            }
            o[ii] = acc;
        }
    }
    grid.sync();

    // ======== P3: CSR scatter ========
    if (bid < 32) {
        int e = bid * 512 + t;
        int d = a.ei[EE + e];
        int slot = atomicAdd(&a.cursor[d], 1);
        a.csr[slot] = a.ei[e];
    }
    grid.sync();

    // ======== P4: gather1 + relu + GCN2 mm (128 blk x 4 rows) ========
    if (bid < 128) {
        float* sh_h = smem;                      // [4][128]
        int j = t & 127, r = t >> 7;
        int row = bid * 4 + r;
        float g = gather_row(a.pre1, a.dinv, a.offs, a.csr, row, j);
        sh_h[r * HID + j] = fmaxf(g + a.g1b[j], 0.0f);
        __syncthreads();
        float acc = 0.0f;
#pragma unroll 8
        for (int k = 0; k < HID; k++)
            acc = fmaf(sh_h[r * HID + k], a.g2w[k * HID + j], acc);
        a.pre2[row * HID + j] = acc;
    }
    grid.sync();

    // ======== P5: gather2 + ca0/ca1 + LN.LN -> t0 (128 blk x 4 rows) ========
    if (bid < 128) {
        float* sh_h = smem;                      // 512 floats
        float* shln = smem + 512;                // 16
        int j = t & 127, r = t >> 7;
        int row = bid * 4 + r;
        float g = gather_row(a.pre2, a.dinv, a.offs, a.csr, row, j);
        sh_h[r * HID + j] = fmaxf(g + a.g2b[j], 0.0f);
        __syncthreads();
        float c0 = a.Mfc0[128 * HID + j], c1 = a.Mfc1[128 * HID + j];
#pragma unroll 4
        for (int k = 0; k < HID; k++) {
            float hk = sh_h[r * HID + k];
            c0 = fmaf(hk, a.Mfc0[k * HID + j], c0);
            c1 = fmaf(hk, a.Mfc1[k * HID + j], c1);
        }
        a.ca1[row * HID + j] = c1;
        float v = rowln4(a.sa0bias[j], a.lnw[j], a.lnb[j], shln, t);
        v = rowln4(v + c0, a.lnw[HID + j], a.lnb[HID + j], shln, t);
        a.t0[row * HID + j] = v;
    }
    grid.sync();

    // ======== P6: FF layer 0 (all 256 blk) ========
    ff_block(a.t0, a.fw1, a.fb1, a.fw2, a.part, smem, bid, t);
    grid.sync();

    // ======== P7: reduce + LN2 + sa1 + LN3 + LN4 -> t2 (128 blk x 4 rows) ========
    if (bid < 128) {
        float* sh_t1 = smem;                     // 512 floats
        float* shln = smem + 512;                // 16
        int j = t & 127, r = t >> 7;
        int row = bid * 4 + r;
        float v = a.fb2[j] + a.t0[row * HID + j];
#pragma unroll
        for (int s = 0; s < 8; s++) v += a.part[s * (NN * HID) + row * HID + j];
        v = rowln4(v, a.lnw[2 * HID + j], a.lnb[2 * HID + j], shln, t);
        sh_t1[r * HID + j] = v;
        __syncthreads();
        float s1 = a.Msa1[128 * HID + j];
#pragma unroll 8
        for (int k = 0; k < HID; k++)
            s1 = fmaf(sh_t1[r * HID + k], a.Msa1[k * HID + j], s1);
        float u = rowln4(v + s1, a.lnw[3 * HID + j], a.lnb[3 * HID + j], shln, t);
        u = rowln4(u + a.ca1[row * HID + j], a.lnw[4 * HID + j], a.lnb[4 * HID + j], shln, t);
        a.t2[row * HID + j] = u;
    }
    grid.sync();

    // ======== P8: FF layer 1 (all 256 blk) ========
    ff_block(a.t2, a.fw1 + HID * FFD, a.fb1 + FFD, a.fw2 + FFD * HID, a.part, smem, bid, t);
    grid.sync();

    // ======== P9: reduce + LN5 + logits + broadcast (128 blk x 4 rows) ========
    if (bid < 128) {
        float* sh3 = smem;                       // 512 floats
        float* shln = smem + 512;                // 16
        float* sh_lg = smem + 528;               // 200 floats (byte 2112, 16B aligned)
        int j = t & 127, r = t >> 7;
        int row = bid * 4 + r;
        float v = a.fb2[HID + j] + a.t2[row * HID + j];
#pragma unroll
        for (int s = 0; s < 8; s++) v += a.part[s * (NN * HID) + row * HID + j];
        v = rowln4(v, a.lnw[5 * HID + j], a.lnb[5 * HID + j], shln, t);
        sh3[r * HID + j] = v;
        __syncthreads();
        if (j < VOCAB) {
            float acc = a.ob[j];
#pragma unroll 8
            for (int k = 0; k < HID; k++)
                acc = fmaf(sh3[r * HID + k], a.ow[k * VOCAB + j], acc);
            sh_lg[r * VOCAB + j] = acc;
        }
        __syncthreads();
        int base = bid * (4 * VOCAB);            // bid*200 floats, 800B aligned
        const float4* lg4 = (const float4*)sh_lg;  // 50 float4
        for (int idx = t; idx < SEQ * 50; idx += 512) {
            int s = idx / 50, q = idx - s * 50;
            *(float4*)&a.out[s * (NN * VOCAB) + base + q * 4] = lg4[q];
        }
    }
}

// ---------------- launch ----------------

extern "C" void kernel_launch(void* const* d_in, const int* in_sizes, int n_in,
                              void* d_out, int out_size, void* d_ws, size_t ws_size,
                              hipStream_t stream) {
    (void)in_sizes; (void)n_in; (void)out_size; (void)ws_size;
    GArgs a;
    a.x   = (const float*)d_in[0];
    a.ei  = (const int*)d_in[1];
    a.g1w = (const float*)d_in[2];
    a.g1b = (const float*)d_in[3];
    a.g2w = (const float*)d_in[4];
    a.g2b = (const float*)d_in[5];
    a.fcw = (const float*)d_in[6];
    a.fcb = (const float*)d_in[7];
    a.saw = (const float*)d_in[8];
    a.sab = (const float*)d_in[9];
    a.caw = (const float*)d_in[10];
    a.cab = (const float*)d_in[11];
    a.lnw = (const float*)d_in[12];
    a.lnb = (const float*)d_in[13];
    a.fw1 = (const float*)d_in[14];
    a.fb1 = (const float*)d_in[15];
    a.fw2 = (const float*)d_in[16];
    a.fb2 = (const float*)d_in[17];
    a.ow  = (const float*)d_in[18];
    a.ob  = (const float*)d_in[19];
    a.out = (float*)d_out;

    float* ws = (float*)d_ws;
    a.pre1    = ws;                 // 65536
    a.pre2    = ws + 65536;         // 65536
    a.t0      = ws + 131072;        // 65536
    a.t2      = ws + 196608;        // 65536
    a.ca1     = ws + 262144;        // 65536
    a.Msa1    = ws + 327680;        // 16512
    a.Mca0    = ws + 344192;        // 16512
    a.Mca1    = ws + 360704;        // 16512
    a.Mfc0    = ws + 377216;        // 16512
    a.Mfc1    = ws + 393728;        // 16512
    a.sa0bias = ws + 410240;        // 128
    a.dinv    = ws + 410368;        // 512
    a.cnt     = (int*)(ws + 410880);   // 512
    a.offs    = a.cnt + 512;           // 513 (+pad)
    a.cursor  = a.offs + 516;          // 512
    a.csr     = a.cursor + 512;        // 16384
    a.part    = ws + 429056;        // 8*65536 = 524288

    hipMemsetAsync(a.cnt, 0, 512 * sizeof(int), stream);

    void* args[] = { &a };
    hipLaunchCooperativeKernel((const void*)k_mega, dim3(256), dim3(512),
                               args, 0, stream);
}

// Round 10
// 123.138 us; speedup vs baseline: 2.7607x; 2.7607x over previous
//
#include <hip/hip_runtime.h>
#include <math.h>

#define NN      512
#define EE      16384
#define NDIM    64
#define HID     128
#define FFD     2048
#define VOCAB   50
#define SEQ     100

// quantum embedding constants: (cos(.05)-sin(.05)), cos(.1), sin(.1)
#define QA 0.94877109112428797f
#define QB 0.99500416527802582f
#define QC 0.099833416646828155f

struct GArgs {
    const int* ei;
    const float* x; const float* g1w; const float* g1b;
    const float* g2w; const float* g2b;
    const float* fcw; const float* fcb;
    const float* saw; const float* sab;
    const float* caw; const float* cab;
    const float* lnw; const float* lnb;
    const float* fw1; const float* fb1; const float* fw2; const float* fb2;
    const float* ow; const float* ob;
    float* out;
    int* offs; int* csr;
    float* dinv; float* pre1; float* pre2; float* t2;
    float* Msa1; float* Mca0; float* Mca1; float* sa0bias;
};

// ---------------- helpers ----------------

__device__ __forceinline__ float gather_row(const float* __restrict__ pre,
                                            const float* __restrict__ dinv,
                                            const int* __restrict__ offs,
                                            const int* __restrict__ csr,
                                            int row, int j) {
    float dd = dinv[row];
    float acc = pre[row * HID + j] * dd;
    int i = offs[row], e = offs[row + 1];
    for (; i + 3 < e; i += 4) {
        int s0 = csr[i], s1 = csr[i + 1], s2 = csr[i + 2], s3 = csr[i + 3];
        float a0 = pre[s0 * HID + j] * dinv[s0];
        float a1 = pre[s1 * HID + j] * dinv[s1];
        float a2 = pre[s2 * HID + j] * dinv[s2];
        float a3 = pre[s3 * HID + j] * dinv[s3];
        acc += (a0 + a1) + (a2 + a3);
    }
    for (; i < e; ++i) {
        int s = csr[i];
        acc += pre[s * HID + j] * dinv[s];
    }
    return acc * dd;
}

// layernorm for 4-rows-per-512-thread-block layout; sh = 16 floats scratch
__device__ __forceinline__ float rowln4(float v, float w, float b, float* sh, int t) {
    int r = t >> 7;
    float s1 = v, s2 = v * v;
#pragma unroll
    for (int o = 32; o > 0; o >>= 1) {
        s1 += __shfl_down(s1, o);
        s2 += __shfl_down(s2, o);
    }
    int wv = (t >> 6) & 1;
    if ((t & 63) == 0) { sh[r * 4 + wv] = s1; sh[r * 4 + 2 + wv] = s2; }
    __syncthreads();
    float mean = (sh[r * 4] + sh[r * 4 + 1]) * (1.0f / HID);
    float m2   = (sh[r * 4 + 2] + sh[r * 4 + 3]) * (1.0f / HID);
    float rstd = rsqrtf(m2 - mean * mean + 1e-5f);
    float out = (v - mean) * rstd * w + b;
    __syncthreads();
    return out;
}

// full-K FF core for 4 rows: sh_x[4][128] -> mid sh_m[4][2048] -> returns
// FF2 output element for (r = t>>7, j = t&127). sh_m is clobbered.
__device__ __forceinline__ float ff_core(const float* __restrict__ W1,
                                         const float* __restrict__ b1,
                                         const float* __restrict__ W2,
                                         const float* sh_x, float* sh_m, int t) {
    // phase 1: mid[4][2048] = relu(x @ W1 + b1); thread owns 1 float4 col x 4 rows
    {
        int c4 = t * 4;
        float4 bb = *(const float4*)&b1[c4];
        float a0x = bb.x, a0y = bb.y, a0z = bb.z, a0w = bb.w;
        float a1x = bb.x, a1y = bb.y, a1z = bb.z, a1w = bb.w;
        float a2x = bb.x, a2y = bb.y, a2z = bb.z, a2w = bb.w;
        float a3x = bb.x, a3y = bb.y, a3z = bb.z, a3w = bb.w;
        const float* w1p = W1 + c4;
#pragma unroll 4
        for (int k = 0; k < HID; k++) {
            float4 w = *(const float4*)&w1p[k * FFD];
            float s0 = sh_x[0 * HID + k], s1 = sh_x[1 * HID + k];
            float s2 = sh_x[2 * HID + k], s3 = sh_x[3 * HID + k];
            a0x = fmaf(s0, w.x, a0x); a0y = fmaf(s0, w.y, a0y);
            a0z = fmaf(s0, w.z, a0z); a0w = fmaf(s0, w.w, a0w);
            a1x = fmaf(s1, w.x, a1x); a1y = fmaf(s1, w.y, a1y);
            a1z = fmaf(s1, w.z, a1z); a1w = fmaf(s1, w.w, a1w);
            a2x = fmaf(s2, w.x, a2x); a2y = fmaf(s2, w.y, a2y);
            a2z = fmaf(s2, w.z, a2z); a2w = fmaf(s2, w.w, a2w);
            a3x = fmaf(s3, w.x, a3x); a3y = fmaf(s3, w.y, a3y);
            a3z = fmaf(s3, w.z, a3z); a3w = fmaf(s3, w.w, a3w);
        }
        float4 m;
        m.x = fmaxf(a0x, 0.f); m.y = fmaxf(a0y, 0.f); m.z = fmaxf(a0z, 0.f); m.w = fmaxf(a0w, 0.f);
        *(float4*)&sh_m[0 * FFD + c4] = m;
        m.x = fmaxf(a1x, 0.f); m.y = fmaxf(a1y, 0.f); m.z = fmaxf(a1z, 0.f); m.w = fmaxf(a1w, 0.f);
        *(float4*)&sh_m[1 * FFD + c4] = m;
        m.x = fmaxf(a2x, 0.f); m.y = fmaxf(a2y, 0.f); m.z = fmaxf(a2z, 0.f); m.w = fmaxf(a2w, 0.f);
        *(float4*)&sh_m[2 * FFD + c4] = m;
        m.x = fmaxf(a3x, 0.f); m.y = fmaxf(a3y, 0.f); m.z = fmaxf(a3z, 0.f); m.w = fmaxf(a3w, 0.f);
        *(float4*)&sh_m[3 * FFD + c4] = m;
    }
    __syncthreads();

    // phase 2: out4[4][128] = mid @ W2, K split 16 ways (kq = t>>5), 4 cols/thread
    float4 p0 = {0, 0, 0, 0}, p1 = p0, p2 = p0, p3 = p0;
    {
        int col4 = (t & 31) * 4, k0 = (t >> 5) * 128;
        const float* w2p = W2 + col4;
#pragma unroll 8
        for (int kk = 0; kk < 128; kk++) {
            int k = k0 + kk;
            float4 w = *(const float4*)&w2p[k * HID];
            float m0 = sh_m[0 * FFD + k], m1 = sh_m[1 * FFD + k];
            float m2 = sh_m[2 * FFD + k], m3 = sh_m[3 * FFD + k];
            p0.x = fmaf(m0, w.x, p0.x); p0.y = fmaf(m0, w.y, p0.y);
            p0.z = fmaf(m0, w.z, p0.z); p0.w = fmaf(m0, w.w, p0.w);
            p1.x = fmaf(m1, w.x, p1.x); p1.y = fmaf(m1, w.y, p1.y);
            p1.z = fmaf(m1, w.z, p1.z); p1.w = fmaf(m1, w.w, p1.w);
            p2.x = fmaf(m2, w.x, p2.x); p2.y = fmaf(m2, w.y, p2.y);
            p2.z = fmaf(m2, w.z, p2.z); p2.w = fmaf(m2, w.w, p2.w);
            p3.x = fmaf(m3, w.x, p3.x); p3.y = fmaf(m3, w.y, p3.y);
            p3.z = fmaf(m3, w.z, p3.z); p3.w = fmaf(m3, w.w, p3.w);
        }
    }
    __syncthreads();                 // all mid reads done before clobbering sh_m
    {
        int col4 = (t & 31) * 4, kq = t >> 5;
        *(float4*)&sh_m[kq * 512 + 0 * 128 + col4] = p0;
        *(float4*)&sh_m[kq * 512 + 1 * 128 + col4] = p1;
        *(float4*)&sh_m[kq * 512 + 2 * 128 + col4] = p2;
        *(float4*)&sh_m[kq * 512 + 3 * 128 + col4] = p3;
    }
    __syncthreads();
    int j = t & 127, r = t >> 7;
    float v = 0.0f;
#pragma unroll
    for (int kq = 0; kq < 16; kq++) v += sh_m[kq * 512 + r * 128 + j];
    return v;
}

// ---------------- kernel A: CSR build | mm1 | comb1 x3 | sa0bias ----------------

__global__ __launch_bounds__(512) void k_a(GArgs a) {
    __shared__ __align__(16) float smem[1024];
    int bid = blockIdx.x, t = threadIdx.x;
    if (bid == 0) {                            // single-block CSR: hist -> scan -> scatter
        int* scnt = (int*)smem;                // 512
        int* scur = scnt + 512;                // 512
        scnt[t] = 0;
        __syncthreads();
#pragma unroll
        for (int i = 0; i < 32; i++) {
            int e = i * 512 + t;
            atomicAdd(&scnt[a.ei[EE + e]], 1);
        }
        __syncthreads();
        int c = scnt[t];
        int v = c;
        for (int o = 1; o < 512; o <<= 1) {
            int add = (t >= o) ? scnt[t - o] : 0;
            __syncthreads();
            v += add;
            scnt[t] = v;
            __syncthreads();
        }
        a.offs[t + 1] = v;
        if (t == 0) a.offs[0] = 0;
        scur[t] = v - c;
        a.dinv[t] = rsqrtf((float)c + 1.0f);
        __syncthreads();
#pragma unroll
        for (int i = 0; i < 32; i++) {
            int e = i * 512 + t;
            int d = a.ei[EE + e];
            int slot = atomicAdd(&scur[d], 1);
            a.csr[slot] = a.ei[e];
        }
    } else if (bid <= 64) {                    // mm1: 8 rows, inline quantum embedding
        float* qxs = smem;                     // 512 floats
        int row0 = (bid - 1) * 8;
        float vx = a.x[row0 * NDIM + t];
        qxs[t] = QA * (QB * vx + QC * tanhf(vx));
        __syncthreads();
        int col = t & 127, r0 = t >> 7;
#pragma unroll
        for (int rr = 0; rr < 2; rr++) {
            int r = r0 + rr * 4;
            float acc = 0.0f;
#pragma unroll 8
            for (int k = 0; k < NDIM; k++)
                acc = fmaf(qxs[r * 64 + k], a.g1w[k * HID + col], acc);
            a.pre1[(row0 + r) * HID + col] = acc;
        }
    } else if (bid <= 163) {                   // comb1: 33 blocks per matrix
        int q = bid - 65;
        int jm = q / 33;
        int i = (q - jm * 33) * 512 + t;
        if (i < 129 * HID) {
            const float* A  = (jm == 0) ? (a.saw + (4 + 2) * HID * HID)
                             : (jm == 1) ? (a.caw + 2 * HID * HID)
                                         : (a.caw + (4 + 2) * HID * HID);
            const float* ab = (jm == 0) ? (a.sab + (4 + 2) * HID)
                             : (jm == 1) ? (a.cab + 2 * HID)
                                         : (a.cab + (4 + 2) * HID);
            const float* Bm = (jm == 0) ? (a.saw + (4 + 3) * HID * HID)
                             : (jm == 1) ? (a.caw + 3 * HID * HID)
                                         : (a.caw + (4 + 3) * HID * HID);
            const float* bb = (jm == 0) ? (a.sab + (4 + 3) * HID)
                             : (jm == 1) ? (a.cab + 3 * HID)
                                         : (a.cab + (4 + 3) * HID);
            float* outM = (jm == 0) ? a.Msa1 : (jm == 1) ? a.Mca0 : a.Mca1;
            int rw = i >> 7, col = i & 127;
            float acc;
            if (rw < 128) {
                const float* ar = A + rw * HID;
                acc = 0.0f;
#pragma unroll 8
                for (int k = 0; k < HID; k++) acc = fmaf(ar[k], Bm[k * HID + col], acc);
            } else {
                acc = bb[col];
#pragma unroll 8
                for (int k = 0; k < HID; k++) acc = fmaf(ab[k], Bm[k * HID + col], acc);
            }
            outM[i] = acc;
        }
    } else {                                   // bid == 164: sa0 bias row
        if (t < HID) {
            const float* ab3 = a.sab + 2 * HID;
            const float* B3  = a.saw + 3 * HID * HID;
            float acc = a.sab[3 * HID + t];
#pragma unroll 8
            for (int k = 0; k < HID; k++) acc = fmaf(ab3[k], B3[k * HID + t], acc);
            a.sa0bias[t] = acc;
        }
    }
}

// ---------------- kernel B: gather1 + relu + GCN2 mm (128 blk x 4 rows) ----------------

__global__ __launch_bounds__(512) void k_b2(GArgs a) {
    __shared__ float sh_h[4 * HID];
    int t = threadIdx.x, j = t & 127, r = t >> 7;
    int row = blockIdx.x * 4 + r;
    float g = gather_row(a.pre1, a.dinv, a.offs, a.csr, row, j);
    sh_h[r * HID + j] = fmaxf(g + a.g1b[j], 0.0f);
    __syncthreads();
    float acc = 0.0f;
#pragma unroll 8
    for (int k = 0; k < HID; k++)
        acc = fmaf(sh_h[r * HID + k], a.g2w[k * HID + j], acc);
    a.pre2[row * HID + j] = acc;
}

// ------- kernel ffA: gather2+memv+ca+LN.LN -> t0 (LDS), FF layer 0, row1 -> t2 -------

__global__ __launch_bounds__(512) void k_ffA(GArgs a) {
    __shared__ __align__(16) float sh_x[4 * HID];   // t0 rows
    __shared__ __align__(16) float sh_h[4 * HID];   // h / memv / t1 scratch
    __shared__ __align__(16) float sh_ca[4 * HID];  // ca1 rows
    __shared__ __align__(16) float sh_m[4 * FFD];   // mid / partials (32 KB)
    __shared__ float shln[16];
    int bid = blockIdx.x, t = threadIdx.x;
    int j = t & 127, r = t >> 7;
    int row = bid * 4 + r;

    // prologue: gather2 + relu -> h
    float g = gather_row(a.pre2, a.dinv, a.offs, a.csr, row, j);
    sh_h[r * HID + j] = fmaxf(g + a.g2b[j], 0.0f);
    __syncthreads();
    // memv = h @ fcw + fcb
    float mv = a.fcb[j];
#pragma unroll 8
    for (int k = 0; k < HID; k++) mv = fmaf(sh_h[r * HID + k], a.fcw[k * HID + j], mv);
    __syncthreads();
    sh_h[r * HID + j] = mv;
    __syncthreads();
    // ca_l = memv @ Mca_l + bias-row
    float c0 = a.Mca0[128 * HID + j], c1 = a.Mca1[128 * HID + j];
#pragma unroll 4
    for (int k = 0; k < HID; k++) {
        float m = sh_h[r * HID + k];
        c0 = fmaf(m, a.Mca0[k * HID + j], c0);
        c1 = fmaf(m, a.Mca1[k * HID + j], c1);
    }
    sh_ca[r * HID + j] = c1;
    float v0 = rowln4(a.sa0bias[j], a.lnw[j], a.lnb[j], shln, t);
    v0 = rowln4(v0 + c0, a.lnw[HID + j], a.lnb[HID + j], shln, t);
    sh_x[r * HID + j] = v0;
    __syncthreads();

    // FF layer 0 (full K, in-block)
    float v = ff_core(a.fw1, a.fb1, a.fw2, sh_x, sh_m, t);

    // row1 epilogue: +bias+residual, LN2, sa1 GEMV, LN3, LN4 -> t2
    v += a.fb2[j] + sh_x[r * HID + j];
    float t1 = rowln4(v, a.lnw[2 * HID + j], a.lnb[2 * HID + j], shln, t);
    __syncthreads();
    sh_h[r * HID + j] = t1;
    __syncthreads();
    float s1 = a.Msa1[128 * HID + j];
#pragma unroll 8
    for (int k = 0; k < HID; k++)
        s1 = fmaf(sh_h[r * HID + k], a.Msa1[k * HID + j], s1);
    float u = rowln4(t1 + s1, a.lnw[3 * HID + j], a.lnb[3 * HID + j], shln, t);
    u = rowln4(u + sh_ca[r * HID + j], a.lnw[4 * HID + j], a.lnb[4 * HID + j], shln, t);
    a.t2[row * HID + j] = u;
}

// ------- kernel ffB: FF layer 1 (full K), LN5, logits, broadcast over SEQ -------

__global__ __launch_bounds__(512) void k_ffB(GArgs a) {
    __shared__ __align__(16) float sh_x[4 * HID];
    __shared__ __align__(16) float sh_h[4 * HID];
    __shared__ __align__(16) float sh_m[4 * FFD];
    __shared__ __align__(16) float sh_lg[4 * VOCAB];
    __shared__ float shln[16];
    int bid = blockIdx.x, t = threadIdx.x;
    int j = t & 127, r = t >> 7;

    if (t < 128) ((float4*)sh_x)[t] = ((const float4*)(a.t2 + bid * 4 * HID))[t];
    __syncthreads();

    float v = ff_core(a.fw1 + HID * FFD, a.fb1 + FFD, a.fw2 + FFD * HID, sh_x, sh_m, t);

    v += a.fb2[HID + j] + sh_x[r * HID + j];
    float w = rowln4(v, a.lnw[5 * HID + j], a.lnb[5 * HID + j], shln, t);
    __syncthreads();
    sh_h[r * HID + j] = w;
    __syncthreads();
    if (t < 4 * VOCAB) {
        int rr = t / VOCAB, c = t - rr * VOCAB;
        float acc = a.ob[c];
#pragma unroll 8
        for (int k = 0; k < HID; k++)
            acc = fmaf(sh_h[rr * HID + k], a.ow[k * VOCAB + c], acc);
        sh_lg[rr * VOCAB + c] = acc;
    }
    __syncthreads();
    // broadcast: 4 rows = 200 contiguous floats (50 float4) per seq position
    const float4* lg4 = (const float4*)sh_lg;
    float4* out4 = (float4*)a.out;
    int base4 = bid * 50;
    for (int idx = t; idx < SEQ * 50; idx += 512) {
        int s = idx / 50, q = idx - s * 50;
        out4[s * (NN * VOCAB / 4) + base4 + q] = lg4[q];
    }
}

// ---------------- launch ----------------

extern "C" void kernel_launch(void* const* d_in, const int* in_sizes, int n_in,
                              void* d_out, int out_size, void* d_ws, size_t ws_size,
                              hipStream_t stream) {
    (void)in_sizes; (void)n_in; (void)out_size; (void)ws_size;
    GArgs a;
    a.x   = (const float*)d_in[0];
    a.ei  = (const int*)d_in[1];
    a.g1w = (const float*)d_in[2];
    a.g1b = (const float*)d_in[3];
    a.g2w = (const float*)d_in[4];
    a.g2b = (const float*)d_in[5];
    a.fcw = (const float*)d_in[6];
    a.fcb = (const float*)d_in[7];
    a.saw = (const float*)d_in[8];
    a.sab = (const float*)d_in[9];
    a.caw = (const float*)d_in[10];
    a.cab = (const float*)d_in[11];
    a.lnw = (const float*)d_in[12];
    a.lnb = (const float*)d_in[13];
    a.fw1 = (const float*)d_in[14];
    a.fb1 = (const float*)d_in[15];
    a.fw2 = (const float*)d_in[16];
    a.fb2 = (const float*)d_in[17];
    a.ow  = (const float*)d_in[18];
    a.ob  = (const float*)d_in[19];
    a.out = (float*)d_out;

    float* ws = (float*)d_ws;
    a.pre1    = ws;                 // 65536
    a.pre2    = ws + 65536;         // 65536
    a.t2      = ws + 131072;        // 65536
    a.Msa1    = ws + 196608;        // 16512
    a.Mca0    = ws + 213120;        // 16512
    a.Mca1    = ws + 229632;        // 16512
    a.sa0bias = ws + 246144;        // 128
    a.dinv    = ws + 246272;        // 512
    a.offs    = (int*)(ws + 246784);   // 513 (+3 pad)
    a.csr     = a.offs + 516;          // 16384

    k_a  <<<165, 512, 0, stream>>>(a);
    k_b2 <<<128, 512, 0, stream>>>(a);
    k_ffA<<<128, 512, 0, stream>>>(a);
    k_ffB<<<128, 512, 0, stream>>>(a);
}

// Round 11
// 114.530 us; speedup vs baseline: 2.9682x; 1.0752x over previous
//
#include <hip/hip_runtime.h>
#include <math.h>

#define NN      512
#define EE      16384
#define NDIM    64
#define HID     128
#define FFD     2048
#define VOCAB   50
#define SEQ     100

// quantum embedding constants: (cos(.05)-sin(.05)), cos(.1), sin(.1)
#define QA 0.94877109112428797f
#define QB 0.99500416527802582f
#define QC 0.099833416646828155f

struct GArgs {
    const int* ei;
    const float* x; const float* g1w; const float* g1b;
    const float* g2w; const float* g2b;
    const float* fcw; const float* fcb;
    const float* saw; const float* sab;
    const float* caw; const float* cab;
    const float* lnw; const float* lnb;
    const float* fw1; const float* fb1; const float* fw2; const float* fb2;
    const float* ow; const float* ob;
    float* out;
    int* offs; int* csr;
    float* dinv; float* pre1; float* pre2; float* t0; float* ca1; float* t2;
    float* Msa1; float* Mca0; float* Mca1; float* sa0bias;
};

// ---------------- helpers ----------------

__device__ __forceinline__ float gather_row(const float* __restrict__ pre,
                                            const float* __restrict__ dinv,
                                            const int* __restrict__ offs,
                                            const int* __restrict__ csr,
                                            int row, int j) {
    float dd = dinv[row];
    float acc = pre[row * HID + j] * dd;
    int i = offs[row], e = offs[row + 1];
    for (; i + 3 < e; i += 4) {
        int s0 = csr[i], s1 = csr[i + 1], s2 = csr[i + 2], s3 = csr[i + 3];
        float a0 = pre[s0 * HID + j] * dinv[s0];
        float a1 = pre[s1 * HID + j] * dinv[s1];
        float a2 = pre[s2 * HID + j] * dinv[s2];
        float a3 = pre[s3 * HID + j] * dinv[s3];
        acc += (a0 + a1) + (a2 + a3);
    }
    for (; i < e; ++i) {
        int s = csr[i];
        acc += pre[s * HID + j] * dinv[s];
    }
    return acc * dd;
}

// layernorm: 128-thread row groups, r = t>>7 (duplicate groups compute same stats)
__device__ __forceinline__ float rowln4(float v, float w, float b, float* sh, int t) {
    int r = t >> 7;
    float s1 = v, s2 = v * v;
#pragma unroll
    for (int o = 32; o > 0; o >>= 1) {
        s1 += __shfl_down(s1, o);
        s2 += __shfl_down(s2, o);
    }
    int wv = (t >> 6) & 1;
    if ((t & 63) == 0) { sh[r * 4 + wv] = s1; sh[r * 4 + 2 + wv] = s2; }
    __syncthreads();
    float mean = (sh[r * 4] + sh[r * 4 + 1]) * (1.0f / HID);
    float m2   = (sh[r * 4 + 2] + sh[r * 4 + 3]) * (1.0f / HID);
    float rstd = rsqrtf(m2 - mean * mean + 1e-5f);
    float out = (v - mean) * rstd * w + b;
    __syncthreads();
    return out;
}

// full-K FF core for 2 rows with per-block K-stagger. Returns FF2 output for
// (r = (t>>7)&1, j = t&127); groups t>=256 compute duplicates.
__device__ __forceinline__ float ff2_core(const float* __restrict__ W1,
                                          const float* __restrict__ b1,
                                          const float* __restrict__ W2,
                                          const float* sh_x, float* sh_m,
                                          float* sh_p, int t, int koff) {
    // phase 1: mid[2][2048] = relu(x @ W1 + b1); thread owns 1 float4 col x 2 rows
    {
        int c4 = t * 4;
        float4 bb = *(const float4*)&b1[c4];
        float a0x = bb.x, a0y = bb.y, a0z = bb.z, a0w = bb.w;
        float a1x = bb.x, a1y = bb.y, a1z = bb.z, a1w = bb.w;
        const float* w1p = W1 + c4;
#pragma unroll 8
        for (int kk = 0; kk < HID; kk++) {
            int k = (kk + koff) & (HID - 1);
            float4 w = *(const float4*)&w1p[k * FFD];
            float s0 = sh_x[k], s1 = sh_x[HID + k];
            a0x = fmaf(s0, w.x, a0x); a0y = fmaf(s0, w.y, a0y);
            a0z = fmaf(s0, w.z, a0z); a0w = fmaf(s0, w.w, a0w);
            a1x = fmaf(s1, w.x, a1x); a1y = fmaf(s1, w.y, a1y);
            a1z = fmaf(s1, w.z, a1z); a1w = fmaf(s1, w.w, a1w);
        }
        float4 m;
        m.x = fmaxf(a0x, 0.f); m.y = fmaxf(a0y, 0.f);
        m.z = fmaxf(a0z, 0.f); m.w = fmaxf(a0w, 0.f);
        *(float4*)&sh_m[c4] = m;
        m.x = fmaxf(a1x, 0.f); m.y = fmaxf(a1y, 0.f);
        m.z = fmaxf(a1z, 0.f); m.w = fmaxf(a1w, 0.f);
        *(float4*)&sh_m[FFD + c4] = m;
    }
    __syncthreads();

    // phase 2: out[2][128] = mid @ W2; K split 16 ways (kq = t>>5), staggered
    {
        int kq = t >> 5, col4 = (t & 31) * 4;
        int k0 = kq * 128;
        float4 p0 = {0, 0, 0, 0}, p1 = {0, 0, 0, 0};
        const float* w2p = W2 + col4;
#pragma unroll 8
        for (int kk = 0; kk < 128; kk++) {
            int k = k0 + ((kk + koff) & 127);
            float4 w = *(const float4*)&w2p[k * HID];
            float m0 = sh_m[k], m1 = sh_m[FFD + k];
            p0.x = fmaf(m0, w.x, p0.x); p0.y = fmaf(m0, w.y, p0.y);
            p0.z = fmaf(m0, w.z, p0.z); p0.w = fmaf(m0, w.w, p0.w);
            p1.x = fmaf(m1, w.x, p1.x); p1.y = fmaf(m1, w.y, p1.y);
            p1.z = fmaf(m1, w.z, p1.z); p1.w = fmaf(m1, w.w, p1.w);
        }
        *(float4*)&sh_p[kq * 256 + col4] = p0;
        *(float4*)&sh_p[kq * 256 + 128 + col4] = p1;
    }
    __syncthreads();
    int j = t & 127, r = (t >> 7) & 1;
    float v = 0.0f;
#pragma unroll
    for (int kq = 0; kq < 16; kq++) v += sh_p[kq * 256 + r * 128 + j];
    return v;
}

// ---------------- kernel A: CSR build | mm1 | comb1 x3 | sa0bias ----------------

__global__ __launch_bounds__(512) void k_a(GArgs a) {
    __shared__ __align__(16) float smem[1024];
    int bid = blockIdx.x, t = threadIdx.x;
    if (bid == 0) {                            // single-block CSR: hist -> scan -> scatter
        int* scnt = (int*)smem;
        int* scur = scnt + 512;
        scnt[t] = 0;
        __syncthreads();
#pragma unroll
        for (int i = 0; i < 32; i++) {
            int e = i * 512 + t;
            atomicAdd(&scnt[a.ei[EE + e]], 1);
        }
        __syncthreads();
        int c = scnt[t];
        int v = c;
        for (int o = 1; o < 512; o <<= 1) {
            int add = (t >= o) ? scnt[t - o] : 0;
            __syncthreads();
            v += add;
            scnt[t] = v;
            __syncthreads();
        }
        a.offs[t + 1] = v;
        if (t == 0) a.offs[0] = 0;
        scur[t] = v - c;
        a.dinv[t] = rsqrtf((float)c + 1.0f);
        __syncthreads();
#pragma unroll
        for (int i = 0; i < 32; i++) {
            int e = i * 512 + t;
            int d = a.ei[EE + e];
            int slot = atomicAdd(&scur[d], 1);
            a.csr[slot] = a.ei[e];
        }
    } else if (bid <= 64) {                    // mm1: 8 rows, inline quantum embedding
        float* qxs = smem;
        int row0 = (bid - 1) * 8;
        float vx = a.x[row0 * NDIM + t];
        qxs[t] = QA * (QB * vx + QC * tanhf(vx));
        __syncthreads();
        int col = t & 127, r0 = t >> 7;
#pragma unroll
        for (int rr = 0; rr < 2; rr++) {
            int r = r0 + rr * 4;
            float acc = 0.0f;
#pragma unroll 8
            for (int k = 0; k < NDIM; k++)
                acc = fmaf(qxs[r * 64 + k], a.g1w[k * HID + col], acc);
            a.pre1[(row0 + r) * HID + col] = acc;
        }
    } else if (bid <= 163) {                   // comb1: 33 blocks per matrix
        int q = bid - 65;
        int jm = q / 33;
        int i = (q - jm * 33) * 512 + t;
        if (i < 129 * HID) {
            const float* A  = (jm == 0) ? (a.saw + (4 + 2) * HID * HID)
                             : (jm == 1) ? (a.caw + 2 * HID * HID)
                                         : (a.caw + (4 + 2) * HID * HID);
            const float* ab = (jm == 0) ? (a.sab + (4 + 2) * HID)
                             : (jm == 1) ? (a.cab + 2 * HID)
                                         : (a.cab + (4 + 2) * HID);
            const float* Bm = (jm == 0) ? (a.saw + (4 + 3) * HID * HID)
                             : (jm == 1) ? (a.caw + 3 * HID * HID)
                                         : (a.caw + (4 + 3) * HID * HID);
            const float* bb = (jm == 0) ? (a.sab + (4 + 3) * HID)
                             : (jm == 1) ? (a.cab + 3 * HID)
                                         : (a.cab + (4 + 3) * HID);
            float* outM = (jm == 0) ? a.Msa1 : (jm == 1) ? a.Mca0 : a.Mca1;
            int rw = i >> 7, col = i & 127;
            float acc;
            if (rw < 128) {
                const float* ar = A + rw * HID;
                acc = 0.0f;
#pragma unroll 8
                for (int k = 0; k < HID; k++) acc = fmaf(ar[k], Bm[k * HID + col], acc);
            } else {
                acc = bb[col];
#pragma unroll 8
                for (int k = 0; k < HID; k++) acc = fmaf(ab[k], Bm[k * HID + col], acc);
            }
            outM[i] = acc;
        }
    } else {                                   // bid == 164: sa0 bias row
        if (t < HID) {
            const float* ab3 = a.sab + 2 * HID;
            const float* B3  = a.saw + 3 * HID * HID;
            float acc = a.sab[3 * HID + t];
#pragma unroll 8
            for (int k = 0; k < HID; k++) acc = fmaf(ab3[k], B3[k * HID + t], acc);
            a.sa0bias[t] = acc;
        }
    }
}

// ---------------- kernel B: gather1 + relu + GCN2 mm (128 blk x 4 rows) ----------------

__global__ __launch_bounds__(512) void k_b2(GArgs a) {
    __shared__ float sh_h[4 * HID];
    int t = threadIdx.x, j = t & 127, r = t >> 7;
    int row = blockIdx.x * 4 + r;
    float g = gather_row(a.pre1, a.dinv, a.offs, a.csr, row, j);
    sh_h[r * HID + j] = fmaxf(g + a.g1b[j], 0.0f);
    __syncthreads();
    float acc = 0.0f;
#pragma unroll 8
    for (int k = 0; k < HID; k++)
        acc = fmaf(sh_h[r * HID + k], a.g2w[k * HID + j], acc);
    a.pre2[row * HID + j] = acc;
}

// ------- kernel C: gather2 + memv(fc) + ca0/ca1 + LN.LN -> t0, ca1 (128 blk x 4 rows) -------

__global__ __launch_bounds__(512) void k_c2(GArgs a) {
    __shared__ __align__(16) float smem[1040];
    float* sh_h = smem;
    float* sh_m = smem + 512;
    float* shln = smem + 1024;
    int t = threadIdx.x, j = t & 127, r = t >> 7;
    int row = blockIdx.x * 4 + r;
    float g = gather_row(a.pre2, a.dinv, a.offs, a.csr, row, j);
    sh_h[r * HID + j] = fmaxf(g + a.g2b[j], 0.0f);
    __syncthreads();
    float mv = a.fcb[j];
#pragma unroll 8
    for (int k = 0; k < HID; k++) mv = fmaf(sh_h[r * HID + k], a.fcw[k * HID + j], mv);
    __syncthreads();
    sh_m[r * HID + j] = mv;
    __syncthreads();
    float c0 = a.Mca0[128 * HID + j], c1 = a.Mca1[128 * HID + j];
#pragma unroll 4
    for (int k = 0; k < HID; k++) {
        float m = sh_m[r * HID + k];
        c0 = fmaf(m, a.Mca0[k * HID + j], c0);
        c1 = fmaf(m, a.Mca1[k * HID + j], c1);
    }
    a.ca1[row * HID + j] = c1;
    float v = rowln4(a.sa0bias[j], a.lnw[j], a.lnb[j], shln, t);
    v = rowln4(v + c0, a.lnw[HID + j], a.lnb[HID + j], shln, t);
    a.t0[row * HID + j] = v;
}

// ------- kernel ffA: FF layer 0 (full K, staggered) + row1 epilogue (256 blk x 2 rows) -------

__global__ __launch_bounds__(512) void k_ffA(GArgs a) {
    __shared__ __align__(16) float sh_x[2 * HID];
    __shared__ __align__(16) float sh_s[2 * HID];
    __shared__ __align__(16) float sh_m[2 * FFD];     // 16 KB
    __shared__ __align__(16) float sh_p[16 * 256];    // 16 KB
    __shared__ float shln[16];
    int bid = blockIdx.x, t = threadIdx.x;
    int row0 = bid * 2;
    if (t < 64) ((float4*)sh_x)[t] = ((const float4*)(a.t0 + row0 * HID))[t];
    __syncthreads();
    int koff = (bid * 37) & 127;
    float v = ff2_core(a.fw1, a.fb1, a.fw2, sh_x, sh_m, sh_p, t, koff);
    int j = t & 127, rr = (t >> 7) & 1;
    v += a.fb2[j] + sh_x[rr * HID + j];
    float t1 = rowln4(v, a.lnw[2 * HID + j], a.lnb[2 * HID + j], shln, t);
    __syncthreads();
    sh_s[rr * HID + j] = t1;                   // dup groups write same value
    __syncthreads();
    float s1 = a.Msa1[128 * HID + j];
#pragma unroll 8
    for (int k = 0; k < HID; k++)
        s1 = fmaf(sh_s[rr * HID + k], a.Msa1[k * HID + j], s1);
    float u = rowln4(t1 + s1, a.lnw[3 * HID + j], a.lnb[3 * HID + j], shln, t);
    u = rowln4(u + a.ca1[(row0 + rr) * HID + j],
               a.lnw[4 * HID + j], a.lnb[4 * HID + j], shln, t);
    if (t < 256) a.t2[(row0 + rr) * HID + j] = u;
}

// ------- kernel ffB: FF layer 1 (full K, staggered) + LN5 + logits + broadcast -------

__global__ __launch_bounds__(512) void k_ffB(GArgs a) {
    __shared__ __align__(16) float sh_x[2 * HID];
    __shared__ __align__(16) float sh_s[2 * HID];
    __shared__ __align__(16) float sh_m[2 * FFD];
    __shared__ __align__(16) float sh_p[16 * 256];
    __shared__ __align__(16) float sh_lg[2 * VOCAB];
    __shared__ float shln[16];
    int bid = blockIdx.x, t = threadIdx.x;
    int row0 = bid * 2;
    if (t < 64) ((float4*)sh_x)[t] = ((const float4*)(a.t2 + row0 * HID))[t];
    __syncthreads();
    int koff = (bid * 37) & 127;
    float v = ff2_core(a.fw1 + HID * FFD, a.fb1 + FFD, a.fw2 + FFD * HID,
                       sh_x, sh_m, sh_p, t, koff);
    int j = t & 127, rr = (t >> 7) & 1;
    v += a.fb2[HID + j] + sh_x[rr * HID + j];
    float w = rowln4(v, a.lnw[5 * HID + j], a.lnb[5 * HID + j], shln, t);
    __syncthreads();
    sh_s[rr * HID + j] = w;
    __syncthreads();
    if (t < 2 * VOCAB) {
        int r2 = t / VOCAB, c = t - r2 * VOCAB;
        float acc = a.ob[c];
#pragma unroll 8
        for (int k = 0; k < HID; k++)
            acc = fmaf(sh_s[r2 * HID + k], a.ow[k * VOCAB + c], acc);
        sh_lg[t] = acc;
    }
    __syncthreads();
    // broadcast: 2 rows = 100 floats = 25 float4 per seq position
    const float4* lg4 = (const float4*)sh_lg;
    float4* out4 = (float4*)a.out;
    int base4 = bid * 25;
    for (int idx = t; idx < SEQ * 25; idx += 512) {
        int s = idx / 25, q = idx - s * 25;
        out4[s * (NN * VOCAB / 4) + base4 + q] = lg4[q];
    }
}

// ---------------- launch ----------------

extern "C" void kernel_launch(void* const* d_in, const int* in_sizes, int n_in,
                              void* d_out, int out_size, void* d_ws, size_t ws_size,
                              hipStream_t stream) {
    (void)in_sizes; (void)n_in; (void)out_size; (void)ws_size;
    GArgs a;
    a.x   = (const float*)d_in[0];
    a.ei  = (const int*)d_in[1];
    a.g1w = (const float*)d_in[2];
    a.g1b = (const float*)d_in[3];
    a.g2w = (const float*)d_in[4];
    a.g2b = (const float*)d_in[5];
    a.fcw = (const float*)d_in[6];
    a.fcb = (const float*)d_in[7];
    a.saw = (const float*)d_in[8];
    a.sab = (const float*)d_in[9];
    a.caw = (const float*)d_in[10];
    a.cab = (const float*)d_in[11];
    a.lnw = (const float*)d_in[12];
    a.lnb = (const float*)d_in[13];
    a.fw1 = (const float*)d_in[14];
    a.fb1 = (const float*)d_in[15];
    a.fw2 = (const float*)d_in[16];
    a.fb2 = (const float*)d_in[17];
    a.ow  = (const float*)d_in[18];
    a.ob  = (const float*)d_in[19];
    a.out = (float*)d_out;

    float* ws = (float*)d_ws;
    a.pre1    = ws;                 // 65536
    a.pre2    = ws + 65536;         // 65536
    a.t0      = ws + 131072;        // 65536
    a.ca1     = ws + 196608;        // 65536
    a.t2      = ws + 262144;        // 65536
    a.Msa1    = ws + 327680;        // 16512
    a.Mca0    = ws + 344192;        // 16512
    a.Mca1    = ws + 360704;        // 16512
    a.sa0bias = ws + 377216;        // 128
    a.dinv    = ws + 377344;        // 512
    a.offs    = (int*)(ws + 377856);   // 513 (+3 pad)
    a.csr     = a.offs + 516;          // 16384

    k_a  <<<165, 512, 0, stream>>>(a);
    k_b2 <<<128, 512, 0, stream>>>(a);
    k_c2 <<<128, 512, 0, stream>>>(a);
    k_ffA<<<256, 512, 0, stream>>>(a);
    k_ffB<<<256, 512, 0, stream>>>(a);
}